// Round 2
// 363.328 us; speedup vs baseline: 1.0122x; 1.0122x over previous
//
#include <hip/hip_runtime.h>

// Problem constants (fixed by reference)
#define B_ 4
#define S_ 4096
#define D_ 2048
#define M_ (B_ * S_)   // 16384 rows of x
#define CHUNK 512      // K-chunk staged per LDS buffer
#define XSTR 520       // LDS row stride in halfs: 1040 B (16B-aligned, +4-bank shift/row)

typedef _Float16 v8h __attribute__((ext_vector_type(8)));
typedef _Float16 v4h __attribute__((ext_vector_type(4)));
typedef _Float16 v2h __attribute__((ext_vector_type(2)));
typedef float    v4f __attribute__((ext_vector_type(4)));

// ---------------------------------------------------------------------------
// Phase 1: q,k = fp16(x) @ [Wq;Wk]^T via MFMA 16x16x32 f16, f32 accumulate,
// rounded to fp16. W arrives as f32 (promoted fp16; conversion exact).
// Block = 256 thr (4 waves), one 16-row m-tile. x is staged through LDS:
// coalesced float4 wave-loads (1 KiB/instr), fp16 cvt, double-buffered
// 16x520-half tiles (one barrier per chunk). Waves split each 512-chunk
// 4 ways (4 MFMA steps each); cross-wave LDS tree-reduce at the end.
// A-frag: A[m=lane&15][k=quad*8+j]; B-frag: B[k=quad*8+j][n=lane&15];
// C/D: col=lane&15, row=quad*4+reg.
// Memory-bound on x (134 MB read, ~21 us floor); unchanged this round.
// ---------------------------------------------------------------------------
__global__ __launch_bounds__(256) void qk_proj_kernel(
    const float* __restrict__ x,
    const float* __restrict__ Wq,        // f32 (fp16 values promoted)
    const float* __restrict__ Wk,        // f32
    unsigned short* __restrict__ q_ws,   // fp16 bits [M,8]
    unsigned short* __restrict__ k_ws)   // fp16 bits [M,8]
{
    __shared__ __align__(16) _Float16 xs[2][16 * XSTR];   // 2 x 16.6 KiB

    const int tid  = threadIdx.x;
    const int wave = tid >> 6;
    const int lane = tid & 63;
    const int quad = lane >> 4;
    const int col  = lane & 15;
    const int mbase = blockIdx.x * 16;

    const int srow = tid >> 7;      // staging row parity (0/1)
    const int sc4  = tid & 127;     // staging float4 column (chunk has 128/row)

    const float* wrow = (col < 8) ? (Wq + (size_t)col * D_)
                                  : (Wk + (size_t)(col - 8) * D_);

    // ---- prologue: load + stage chunk 0 into buffer 0 ----
    float4 cur[8];
#pragma unroll
    for (int i = 0; i < 8; ++i) {
        const int row = i * 2 + srow;
        cur[i] = *(const float4*)(x + (size_t)(mbase + row) * D_ + sc4 * 4);
    }
#pragma unroll
    for (int i = 0; i < 8; ++i) {
        const int row = i * 2 + srow;
        v4h p = { (_Float16)cur[i].x, (_Float16)cur[i].y,
                  (_Float16)cur[i].z, (_Float16)cur[i].w };   // RNE = x.half()
        *(v4h*)&xs[0][row * XSTR + sc4 * 4] = p;              // ds_write_b64
    }
    __syncthreads();

    v4f acc = {0.f, 0.f, 0.f, 0.f};

    for (int c = 0; c < 4; ++c) {
        float4 nxt[8];
        if (c < 3) {
#pragma unroll
            for (int i = 0; i < 8; ++i) {
                const int row = i * 2 + srow;
                nxt[i] = *(const float4*)(x + (size_t)(mbase + row) * D_
                                          + (c + 1) * CHUNK + sc4 * 4);
            }
        }
        const _Float16* xbuf = xs[c & 1];
#pragma unroll
        for (int s = 0; s < 4; ++s) {
            const int kloc = wave * 128 + s * 32 + quad * 8;
            v8h a = *(const v8h*)(xbuf + col * XSTR + kloc);  // ds_read_b128
            const int kg = c * CHUNK + kloc;
            float4 w0 = *(const float4*)(wrow + kg);          // L2-hot
            float4 w1 = *(const float4*)(wrow + kg + 4);
            v8h b;
            b[0]=(_Float16)w0.x; b[1]=(_Float16)w0.y;
            b[2]=(_Float16)w0.z; b[3]=(_Float16)w0.w;
            b[4]=(_Float16)w1.x; b[5]=(_Float16)w1.y;
            b[6]=(_Float16)w1.z; b[7]=(_Float16)w1.w;
            acc = __builtin_amdgcn_mfma_f32_16x16x32_f16(a, b, acc, 0, 0, 0);
        }
        if (c < 3) {
            _Float16* dbuf = xs[(c + 1) & 1];
#pragma unroll
            for (int i = 0; i < 8; ++i) {
                const int row = i * 2 + srow;
                v4h p = { (_Float16)nxt[i].x, (_Float16)nxt[i].y,
                          (_Float16)nxt[i].z, (_Float16)nxt[i].w };
                *(v4h*)&dbuf[row * XSTR + sc4 * 4] = p;
            }
            __syncthreads();   // single barrier/chunk: WAR safe (see analysis)
        }
    }

    // ---- cross-wave reduction through LDS (reuse xs) ----
    __syncthreads();
    v4f* red = (v4f*)&xs[0][0];            // 192 v4f = 3 KiB
    if (wave > 0) red[(wave - 1) * 64 + lane] = acc;
    __syncthreads();
    if (wave == 0) {
#pragma unroll
        for (int w = 0; w < 3; ++w) acc += red[w * 64 + lane];
#pragma unroll
        for (int reg = 0; reg < 4; ++reg) {
            const int row = mbase + quad * 4 + reg;
            const unsigned short h =
                __builtin_bit_cast(unsigned short, (_Float16)acc[reg]);
            if (col < 8) q_ws[(size_t)row * 8 + col] = h;
            else         k_ws[(size_t)row * 8 + (col - 8)] = h;
        }
    }
}

// ---------------------------------------------------------------------------
// Phase 2 (rewritten): scores[b][t][s] = f32(relu(fp16(sum_r q[t][r]*k[s][r]))).
// Block = 256 thr; 16 t-rows x 2048 s-cols. NO k LDS tile: each thread owns
// 4 consecutive s-columns per 1024-chunk, loads its 64 B of k ONCE into
// registers (4x global_load_dwordx4, coalesced, L2-hot: 32 KB k-tile shared
// by 256 blocks) and reuses it across all 16 t-rows. q broadcast from a
// 256 B LDS buffer. One float4 nontemporal store per (tl,chunk): 32 dwordx4
// stores/thread vs previous 128 scalar dwords; 8 VMEM k-reads vs previous
// 128 ds_read_b128 (16x redundant LDS traffic eliminated). Write-BW bound:
// 268 MB / ~6.5 TB/s ~= 42 us floor.
// ---------------------------------------------------------------------------
__device__ __forceinline__ float dot8(const uint4 qv, const uint4 kv) {
#if __has_builtin(__builtin_amdgcn_fdot2)
    float d = 0.f;
    d = __builtin_amdgcn_fdot2(__builtin_bit_cast(v2h, qv.x),
                               __builtin_bit_cast(v2h, kv.x), d, false);
    d = __builtin_amdgcn_fdot2(__builtin_bit_cast(v2h, qv.y),
                               __builtin_bit_cast(v2h, kv.y), d, false);
    d = __builtin_amdgcn_fdot2(__builtin_bit_cast(v2h, qv.z),
                               __builtin_bit_cast(v2h, kv.z), d, false);
    d = __builtin_amdgcn_fdot2(__builtin_bit_cast(v2h, qv.w),
                               __builtin_bit_cast(v2h, kv.w), d, false);
    return d;
#else
    const v2h q0 = __builtin_bit_cast(v2h, qv.x);
    const v2h q1 = __builtin_bit_cast(v2h, qv.y);
    const v2h q2 = __builtin_bit_cast(v2h, qv.z);
    const v2h q3 = __builtin_bit_cast(v2h, qv.w);
    const v2h ka = __builtin_bit_cast(v2h, kv.x);
    const v2h kb = __builtin_bit_cast(v2h, kv.y);
    const v2h kc = __builtin_bit_cast(v2h, kv.z);
    const v2h kd = __builtin_bit_cast(v2h, kv.w);
    return (float)q0[0]*(float)ka[0] + (float)q0[1]*(float)ka[1]
         + (float)q1[0]*(float)kb[0] + (float)q1[1]*(float)kb[1]
         + (float)q2[0]*(float)kc[0] + (float)q2[1]*(float)kc[1]
         + (float)q3[0]*(float)kd[0] + (float)q3[1]*(float)kd[1];
#endif
}

__device__ __forceinline__ float relu_h(float d) {
    const float hv = (float)(_Float16)d;   // round dot to fp16 (matches ref)
    return hv > 0.f ? hv : 0.f;
}

__global__ __launch_bounds__(256) void scores_kernel(
    const unsigned short* __restrict__ q_ws,
    const unsigned short* __restrict__ k_ws,
    float* __restrict__ out)
{
    __shared__ unsigned short qsh[16 * 8];   // 256 B: q rows for this t-tile

    const int tid   = threadIdx.x;
    const int tbase = blockIdx.x * 16;
    const int sbase = blockIdx.y * 2048;
    const int b     = blockIdx.z;

    if (tid < 16) {
        ((uint4*)qsh)[tid] =
            *(const uint4*)(q_ws + ((size_t)b * S_ + tbase + tid) * 8);
    }
    __syncthreads();

    float* obase = out + ((size_t)b * S_ + tbase) * (size_t)S_ + sbase;

#pragma unroll
    for (int ch = 0; ch < 2; ++ch) {
        const int s0 = ch * 1024 + tid * 4;           // 4 consecutive s-cols
        const uint4* ksrc =
            (const uint4*)(k_ws + ((size_t)b * S_ + sbase + s0) * 8);
        const uint4 k0 = ksrc[0];                     // 64 B/thread, coalesced
        const uint4 k1 = ksrc[1];                     // (wave = 4 KB contiguous)
        const uint4 k2 = ksrc[2];
        const uint4 k3 = ksrc[3];
        float* ocol = obase + s0;

#pragma unroll 4
        for (int tl = 0; tl < 16; ++tl) {
            const uint4 qv = *(const uint4*)(qsh + tl * 8);  // LDS broadcast
            v4f r;
            r.x = relu_h(dot8(qv, k0));
            r.y = relu_h(dot8(qv, k1));
            r.z = relu_h(dot8(qv, k2));
            r.w = relu_h(dot8(qv, k3));
            __builtin_nontemporal_store(r, (v4f*)(ocol + (size_t)tl * S_));
        }
    }
}

extern "C" void kernel_launch(void* const* d_in, const int* in_sizes, int n_in,
                              void* d_out, int out_size, void* d_ws, size_t ws_size,
                              hipStream_t stream) {
    const float* x  = (const float*)d_in[0];
    const float* Wq = (const float*)d_in[1];   // f32 (promoted fp16)
    const float* Wk = (const float*)d_in[2];   // f32
    float* out = (float*)d_out;                // f32

    unsigned short* q_ws = (unsigned short*)d_ws;    // fp16 bits [M,8]
    unsigned short* k_ws = q_ws + (size_t)M_ * 8;    // fp16 bits [M,8]

    qk_proj_kernel<<<dim3(M_ / 16), dim3(256), 0, stream>>>(x, Wq, Wk, q_ws, k_ws);
    scores_kernel<<<dim3(S_ / 16, 2, B_), dim3(256), 0, stream>>>(q_ws, k_ws, out);
}